// Round 1
// baseline (157.785 us; speedup 1.0000x reference)
//
#include <hip/hip_runtime.h>
#include <hip/hip_bf16.h>
#include <stdint.h>
#include <stddef.h>

// ---------------------------------------------------------------------------
// MyConv2D: fixed-point quantized conv (Width=8), valid 3x3, NHWC, + bias + ReLU
// x:(32,56,56,128) f32, w:(3,3,128,256) f32, bias:(54,54,256) f32
// out:(32,54,54,256) f32
//
// Exactness argument: quantized values are a/256 with |a|<=256 (bf16-exact).
// Products are multiples of 2^-16; all 1152-term partial sums are integers
// (scaled by 2^-16) bounded well below 2^24 -> fp32 MFMA accumulation exact.
// ---------------------------------------------------------------------------

typedef float  f32x4  __attribute__((ext_vector_type(4)));
typedef short  bf16x8 __attribute__((ext_vector_type(8)));

#define N_IMG 32
#define H_IN 56
#define W_IN 56
#define C_IN 128
#define F_OUT 256
#define OHW 54
#define M_TOTAL (N_IMG * OHW * OHW)   // 93312
#define BM 64
#define LDSPAD 40                      // 32 + 8 bf16 pad (80B row stride)

__device__ __forceinline__ unsigned short quant_to_bf16(float x) {
    // clip(round(x*256)/256, -1, 1); round = half-to-even (v_rndne_f32)
    float a = rintf(x * 256.0f);
    a = fminf(fmaxf(a, -256.0f), 256.0f);
    float q = a * 0.00390625f;          // exact in bf16 (int/2^8, |int|<=256)
    union { float f; unsigned int u; } cv; cv.f = q;
    return (unsigned short)(cv.u >> 16); // exact -> truncation is exact
}

__global__ __launch_bounds__(256) void quant_x_kernel(
        const float* __restrict__ x, unsigned short* __restrict__ xq) {
    int i = (blockIdx.x * 256 + threadIdx.x) * 4;
    float4 v = *reinterpret_cast<const float4*>(x + i);
    ushort4 o;
    o.x = quant_to_bf16(v.x);
    o.y = quant_to_bf16(v.y);
    o.z = quant_to_bf16(v.z);
    o.w = quant_to_bf16(v.w);
    *reinterpret_cast<ushort4*>(xq + i) = o;
}

// w (3,3,128,256) -> wp[kk=kh*3+kw][f=256][c=128], quantized bf16
__global__ __launch_bounds__(256) void quant_w_kernel(
        const float* __restrict__ w, unsigned short* __restrict__ wp) {
    int idx = blockIdx.x * 256 + threadIdx.x;     // 9*256*128 = 294912
    int c  = idx & 127;
    int f  = (idx >> 7) & 255;
    int kk = idx >> 15;
    float v = w[(kk * C_IN + c) * F_OUT + f];
    wp[idx] = quant_to_bf16(v);
}

__global__ __launch_bounds__(256, 4) void conv_kernel(
        const unsigned short* __restrict__ xq,   // [32][56][56][128] bf16
        const unsigned short* __restrict__ wp,   // [9][256][128] bf16
        const float* __restrict__ bias,          // [54][54][256]
        float* __restrict__ out)                 // [93312][256]
{
    __shared__ unsigned short Alds[BM][LDSPAD];
    __shared__ unsigned short Blds[F_OUT][LDSPAD];

    const int tid  = threadIdx.x;
    const int wave = tid >> 6;
    const int lane = tid & 63;
    const int m0   = blockIdx.x * BM;

    // --- A staging: thread t stages row (t>>2), 8-bf16 chunk (t&3) ---
    const int arow   = tid >> 2;
    const int achunk = tid & 3;
    {
    }
    const int m_stage = m0 + arow;
    const int n_img = m_stage / (OHW * OHW);
    const int rem   = m_stage % (OHW * OHW);
    const int oh    = rem / OHW;
    const int ow    = rem % OHW;
    const unsigned short* aptr =
        xq + ((size_t)(n_img * H_IN + oh) * W_IN + ow) * C_IN + achunk * 8;

    // --- B staging: thread t stages LDS row f=t (32 c's = 4 x 16B) ---
    const unsigned short* bptr = wp + (size_t)tid * C_IN;

    f32x4 acc[4][4];
#pragma unroll
    for (int i = 0; i < 4; ++i)
#pragma unroll
        for (int j = 0; j < 4; ++j) acc[i][j] = (f32x4)(0.0f);

    const int krow = (lane >> 4) * 8;  // k offset of this lane's fragment
    const int mr   = lane & 15;

    for (int kk = 0; kk < 9; ++kk) {
        const int kh = kk / 3, kw = kk % 3;
        const int aoff = (kh * W_IN + kw) * C_IN;
        const unsigned short* bkk = bptr + (size_t)kk * (F_OUT * C_IN);
#pragma unroll
        for (int cs = 0; cs < 4; ++cs) {
            __syncthreads();
            // stage A: 64 rows x 32 bf16
            bf16x8 av = *reinterpret_cast<const bf16x8*>(aptr + aoff + cs * 32);
            *reinterpret_cast<bf16x8*>(&Alds[arow][achunk * 8]) = av;
            // stage B: 256 rows x 32 bf16
            const unsigned short* bp = bkk + cs * 32;
            bf16x8 bv0 = *reinterpret_cast<const bf16x8*>(bp);
            bf16x8 bv1 = *reinterpret_cast<const bf16x8*>(bp + 8);
            bf16x8 bv2 = *reinterpret_cast<const bf16x8*>(bp + 16);
            bf16x8 bv3 = *reinterpret_cast<const bf16x8*>(bp + 24);
            *reinterpret_cast<bf16x8*>(&Blds[tid][0])  = bv0;
            *reinterpret_cast<bf16x8*>(&Blds[tid][8])  = bv1;
            *reinterpret_cast<bf16x8*>(&Blds[tid][16]) = bv2;
            *reinterpret_cast<bf16x8*>(&Blds[tid][24]) = bv3;
            __syncthreads();

            bf16x8 af[4], bfr[4];
#pragma unroll
            for (int mi = 0; mi < 4; ++mi)
                af[mi] = *reinterpret_cast<const bf16x8*>(&Alds[mi * 16 + mr][krow]);
#pragma unroll
            for (int ni = 0; ni < 4; ++ni)
                bfr[ni] = *reinterpret_cast<const bf16x8*>(
                    &Blds[wave * 64 + ni * 16 + mr][krow]);
#pragma unroll
            for (int mi = 0; mi < 4; ++mi)
#pragma unroll
                for (int ni = 0; ni < 4; ++ni)
                    acc[mi][ni] = __builtin_amdgcn_mfma_f32_16x16x32_bf16(
                        af[mi], bfr[ni], acc[mi][ni], 0, 0, 0);
        }
    }

    // --- epilogue: quantize conv output, add bias, ReLU ---
    const int col0  = wave * 64 + (lane & 15);
    const int rbase = (lane >> 4) * 4;
#pragma unroll
    for (int mi = 0; mi < 4; ++mi) {
#pragma unroll
        for (int r = 0; r < 4; ++r) {
            const int mrow = m0 + mi * 16 + rbase + r;
            const int brow = (mrow % (OHW * OHW)) * F_OUT;
            float* orow = out + (size_t)mrow * F_OUT;
#pragma unroll
            for (int ni = 0; ni < 4; ++ni) {
                float v = acc[mi][ni][r];
                float t = rintf(v * 256.0f);          // acc*256 exact; half-even
                t = fminf(fmaxf(t, -256.0f), 256.0f);
                float q = t * 0.00390625f;
                int f = col0 + ni * 16;
                float o = q + bias[brow + f];
                orow[f] = fmaxf(o, 0.0f);
            }
        }
    }
}

extern "C" void kernel_launch(void* const* d_in, const int* in_sizes, int n_in,
                              void* d_out, int out_size, void* d_ws, size_t ws_size,
                              hipStream_t stream) {
    (void)in_sizes; (void)n_in; (void)out_size;
    const float* x    = (const float*)d_in[0];
    const float* w    = (const float*)d_in[1];
    const float* bias = (const float*)d_in[2];
    float* out        = (float*)d_out;

    const size_t x_elems = (size_t)N_IMG * H_IN * W_IN * C_IN;   // 12,845,056
    const size_t w_elems = (size_t)9 * F_OUT * C_IN;             // 294,912
    const size_t xq_bytes = x_elems * sizeof(unsigned short);    // 25,690,112
    const size_t need = xq_bytes + w_elems * sizeof(unsigned short);
    if (ws_size < need) return;  // workspace too small (would corrupt) -> fail loudly

    unsigned short* xq = (unsigned short*)d_ws;
    unsigned short* wp = (unsigned short*)((char*)d_ws + xq_bytes);

    quant_x_kernel<<<(int)(x_elems / (256 * 4)), 256, 0, stream>>>(x, xq);
    quant_w_kernel<<<(int)(w_elems / 256), 256, 0, stream>>>(w, wp);
    conv_kernel<<<M_TOTAL / BM, 256, 0, stream>>>(xq, wp, bias, out);
}

// Round 2
// 92.800 us; speedup vs baseline: 1.7003x; 1.7003x over previous
//
#include <hip/hip_runtime.h>
#include <hip/hip_bf16.h>
#include <stdint.h>
#include <stddef.h>

// ---------------------------------------------------------------------------
// MyConv2D: fixed-point quantized conv (Width=8), valid 3x3, NHWC, + bias + ReLU
// x:(32,56,56,128) f32, w:(3,3,128,256) f32, bias:(54,54,256) f32
// out:(32,54,54,256) f32
//
// Exactness: quantized values are a/256, |a|<=256 (bf16-exact); all partial
// sums are integer multiples of 2^-16 bounded << 2^24 -> fp32 MFMA exact.
//
// R2: m97-structure implicit GEMM. M=93312, N=256, K=1152 (9 taps x 128c).
// BM=128 BN=128 BK=64, 256 thr (4 waves, 2x2, 64x64/wave), global_load_lds
// width=16, XOR-swizzled LDS (linear dest + pre-swizzled global src + same
// XOR on ds_read_b128) -> 2-way conflicts only.
// ---------------------------------------------------------------------------

typedef float  f32x4  __attribute__((ext_vector_type(4)));
typedef short  bf16x8 __attribute__((ext_vector_type(8)));

#define N_IMG 32
#define H_IN 56
#define W_IN 56
#define C_IN 128
#define F_OUT 256
#define OHW 54
#define M_TOTAL (N_IMG * OHW * OHW)   // 93312 = 729 * 128
#define BM 128
#define BN 128
#define BK 64

__device__ __forceinline__ unsigned short quant_to_bf16(float x) {
    float a = rintf(x * 256.0f);                 // v_rndne: half-to-even, matches jnp.round
    a = fminf(fmaxf(a, -256.0f), 256.0f);
    float q = a * 0.00390625f;                   // exact in bf16
    union { float f; unsigned int u; } cv; cv.f = q;
    return (unsigned short)(cv.u >> 16);
}

__device__ __forceinline__ void async_copy16(const unsigned short* g, unsigned short* l) {
    __builtin_amdgcn_global_load_lds(
        (const __attribute__((address_space(1))) unsigned int*)g,
        (__attribute__((address_space(3))) unsigned int*)l, 16, 0, 0);
}

__global__ __launch_bounds__(256) void quant_x_kernel(
        const float* __restrict__ x, unsigned short* __restrict__ xq) {
    int i = (blockIdx.x * 256 + threadIdx.x) * 4;
    float4 v = *reinterpret_cast<const float4*>(x + i);
    ushort4 o;
    o.x = quant_to_bf16(v.x);
    o.y = quant_to_bf16(v.y);
    o.z = quant_to_bf16(v.z);
    o.w = quant_to_bf16(v.w);
    *reinterpret_cast<ushort4*>(xq + i) = o;
}

// w (3,3,128,256) -> wp[kk][f=256][c=128], quantized bf16 (B^T layout, K-contig)
__global__ __launch_bounds__(256) void quant_w_kernel(
        const float* __restrict__ w, unsigned short* __restrict__ wp) {
    int idx = blockIdx.x * 256 + threadIdx.x;     // 9*256*128
    int c  = idx & 127;
    int f  = (idx >> 7) & 255;
    int kk = idx >> 15;
    float v = w[(kk * C_IN + c) * F_OUT + f];
    wp[idx] = quant_to_bf16(v);
}

__global__ __launch_bounds__(256) void conv_kernel(
        const unsigned short* __restrict__ xq,   // [32][56][56][128] bf16
        const unsigned short* __restrict__ wp,   // [9][256][128] bf16
        const float* __restrict__ bias,          // [54][54][256]
        float* __restrict__ out)                 // [93312][256]
{
    __shared__ __attribute__((aligned(16))) unsigned short Alds[BM * BK]; // 16 KB
    __shared__ __attribute__((aligned(16))) unsigned short Blds[BN * BK]; // 16 KB

    const int tid  = threadIdx.x;
    const int wave = tid >> 6;
    const int lane = tid & 63;
    const int bid  = blockIdx.x;
    const int mb   = bid >> 1;
    const int nb   = bid & 1;
    const int m0   = mb * BM;
    const int wr   = wave >> 1;   // wave row (0..1)
    const int wc   = wave & 1;    // wave col (0..1)

    // ---- staging precompute ----
    // chunk i = r*256 + tid ; row = (tid>>3) + 32*r ; c16 = tid&7
    // swizzled source chunk: c16 ^ (row&7); (row&7) constant across rounds (32*r = 0 mod 8)
    const int c16  = tid & 7;
    const int row0 = tid >> 3;                    // 0..31
    const int sw   = c16 ^ (row0 & 7);

    const unsigned short* a_base[4];
#pragma unroll
    for (int r = 0; r < 4; ++r) {
        int m = m0 + row0 + 32 * r;
        int n_img = m / (OHW * OHW);
        int rem   = m % (OHW * OHW);
        int oh = rem / OHW, ow = rem % OHW;
        a_base[r] = xq + (size_t)((n_img * H_IN + oh) * W_IN + ow) * C_IN + sw * 8;
    }
    const unsigned short* b_base[4];
#pragma unroll
    for (int r = 0; r < 4; ++r) {
        int f = nb * BN + row0 + 32 * r;
        b_base[r] = wp + (size_t)f * C_IN + sw * 8;
    }
    // wave-uniform LDS dest (chunk base), lane offset applied by HW (+lane*16B)
    unsigned short* a_dst[4];
    unsigned short* b_dst[4];
#pragma unroll
    for (int r = 0; r < 4; ++r) {
        int cb = r * 256 + (tid & ~63);
        a_dst[r] = Alds + cb * 8;
        b_dst[r] = Blds + cb * 8;
    }

    // ---- fragment-read lane geometry ----
    const int mr = lane & 15;
    const int lq = lane >> 4;        // 0..3
    const int ls = lane & 7;         // XOR key ( == row&7 for rows mi*16+mr )

    f32x4 acc[4][4];
#pragma unroll
    for (int i = 0; i < 4; ++i)
#pragma unroll
        for (int j = 0; j < 4; ++j) acc[i][j] = (f32x4)(0.0f);

    for (int kk = 0; kk < 9; ++kk) {
        const int kh = kk / 3, kw = kk - 3 * kh;
        const int atap = (kh * W_IN + kw) * C_IN;
        const int btap = kk * (F_OUT * C_IN);
#pragma unroll
        for (int half = 0; half < 2; ++half) {
            const int aoff = atap + half * 64;
            const int boff = btap + half * 64;

            __syncthreads();               // prev compute done reading LDS
#pragma unroll
            for (int r = 0; r < 4; ++r)
                async_copy16(a_base[r] + aoff, a_dst[r]);
#pragma unroll
            for (int r = 0; r < 4; ++r)
                async_copy16(b_base[r] + boff, b_dst[r]);
            __syncthreads();               // compiler drains vmcnt(0) before barrier

#pragma unroll
            for (int ks = 0; ks < 2; ++ks) {
                bf16x8 af[4], bfr[4];
#pragma unroll
                for (int mi = 0; mi < 4; ++mi)
                    af[mi] = *reinterpret_cast<const bf16x8*>(
                        Alds + (wr * 64 + mi * 16 + mr) * BK + (((ks * 4 + lq) ^ ls) * 8));
#pragma unroll
                for (int ni = 0; ni < 4; ++ni)
                    bfr[ni] = *reinterpret_cast<const bf16x8*>(
                        Blds + (wc * 64 + ni * 16 + mr) * BK + (((ks * 4 + lq) ^ ls) * 8));
#pragma unroll
                for (int mi = 0; mi < 4; ++mi)
#pragma unroll
                    for (int ni = 0; ni < 4; ++ni)
                        acc[mi][ni] = __builtin_amdgcn_mfma_f32_16x16x32_bf16(
                            af[mi], bfr[ni], acc[mi][ni], 0, 0, 0);
            }
        }
    }

    // ---- epilogue: quantize, bias, ReLU ----
    const int fcol0 = nb * BN + wc * 64 + mr;
#pragma unroll
    for (int mi = 0; mi < 4; ++mi) {
#pragma unroll
        for (int r = 0; r < 4; ++r) {
            const int m = m0 + wr * 64 + mi * 16 + lq * 4 + r;
            const float* brow = bias + (size_t)(m % (OHW * OHW)) * F_OUT;
            float* orow = out + (size_t)m * F_OUT;
#pragma unroll
            for (int ni = 0; ni < 4; ++ni) {
                float v = acc[mi][ni][r];
                float t = rintf(v * 256.0f);
                t = fminf(fmaxf(t, -256.0f), 256.0f);
                float o = t * 0.00390625f + brow[fcol0 + ni * 16];
                orow[fcol0 + ni * 16] = fmaxf(o, 0.0f);
            }
        }
    }
}

extern "C" void kernel_launch(void* const* d_in, const int* in_sizes, int n_in,
                              void* d_out, int out_size, void* d_ws, size_t ws_size,
                              hipStream_t stream) {
    (void)in_sizes; (void)n_in; (void)out_size;
    const float* x    = (const float*)d_in[0];
    const float* w    = (const float*)d_in[1];
    const float* bias = (const float*)d_in[2];
    float* out        = (float*)d_out;

    const size_t x_elems = (size_t)N_IMG * H_IN * W_IN * C_IN;   // 12,845,056
    const size_t w_elems = (size_t)9 * F_OUT * C_IN;             // 294,912
    const size_t xq_bytes = x_elems * sizeof(unsigned short);
    const size_t need = xq_bytes + w_elems * sizeof(unsigned short);
    if (ws_size < need) return;

    unsigned short* xq = (unsigned short*)d_ws;
    unsigned short* wp = (unsigned short*)((char*)d_ws + xq_bytes);

    quant_x_kernel<<<(int)(x_elems / (256 * 4)), 256, 0, stream>>>(x, xq);
    quant_w_kernel<<<(int)(w_elems / 256), 256, 0, stream>>>(w, wp);
    conv_kernel<<<(M_TOTAL / BM) * 2, 256, 0, stream>>>(xq, wp, bias, out);
}